// Round 15
// baseline (218.816 us; speedup 1.0000x reference)
//
#include <hip/hip_runtime.h>
#include <hip/hip_bf16.h>

// Sggnn_gcn — fused 2x(Linear512+BN+LReLU) + Wc projection, then GCN on 2-wide
// features. Restructuring: (w_norm^T @ t) @ Wc^T == w_norm^T @ (t @ Wc^T).
// v15: barrier-free fused kernel in the 256-reg regime.
//  * Register-granule insight: HW allocates 64/128/256-reg buckets. 64-AGPR acc
//    at 4 waves/SIMD leaves exactly 64 arch VGPRs -> v10-v14's chronic spills.
//    Here: 8-wave blocks (2 waves/SIMD) + __launch_bounds__(512,2) = 256 regs.
//  * __syncthreads drains vmcnt(0) -> cross-barrier prefetch is impossible at
//    HIP level. Fix: remove the barriers. Whole A-tile staged to LDS
//    fragment-major up front; both K-loops are barrier-free (2 barriers/tile).
//  * Persistent 256 blocks x 4 tiles: next tile's A loads are issued before
//    phase 2 and ds-written after it -> HBM latency hides under MFMA.

typedef __hip_bfloat16 bf16_t;
typedef __bf16 bf16x8 __attribute__((ext_vector_type(8)));
typedef __bf16 bf16x4 __attribute__((ext_vector_type(4)));
typedef float f32x4 __attribute__((ext_vector_type(4)));

#define KDIM 512
#define BM 64

__device__ __forceinline__ float ldsel(const void* p, int i, int isbf) {
    return isbf ? __bfloat162float(((const bf16_t*)p)[i]) : ((const float*)p)[i];
}

// ---- probe: detect dtype of d (bf16 vs f32) from exponent statistics ----
__global__ void probe_kernel(const void* __restrict__ d, int* __restrict__ flag) {
    const unsigned short* u = (const unsigned short*)d;
    const int l = threadIdx.x;   // 64
    int cnt = 0;
    for (int i = l; i < 256; i += 64) {
        const int e = (u[i] >> 7) & 0xFF;
        cnt += (e >= 118 && e <= 129) ? 1 : 0;
    }
    #pragma unroll
    for (int off = 32; off; off >>= 1) cnt += __shfl_down(cnt, off, 64);
    if (l == 0) *flag = (cnt >= 200) ? 1 : 0;   // bf16 ~255, f32 ~134
}

// ---- prep: rowsum of adj = w + I  ->  d_inv_sqrt ----
__global__ void rowsum_kernel(const void* __restrict__ w, const int* __restrict__ flagp,
                              float* __restrict__ dinv) {
    const int isbf = *flagp;
    const int i = blockIdx.x;
    const int l = threadIdx.x;
    float s = 0.f;
    for (int j = l; j < 512; j += 64) s += ldsel(w, i * 512 + j, isbf);
    #pragma unroll
    for (int off = 32; off; off >>= 1) s += __shfl_down(s, off, 64);
    if (l == 0) dinv[i] = 1.0f / sqrtf(s + 1.0f);
}

// ---- prep: fold BN -> scale/shift; canonicalize Wc, bc to f32 ----
__global__ void params_kernel(const void* g1, const void* b1, const void* m1,
                              const void* v1, const void* be1,
                              const void* g2, const void* b2, const void* m2,
                              const void* v2, const void* be2,
                              const void* Wc, const void* bc,
                              const int* __restrict__ flagp,
                              float* sc1, float* sh1, float* sc2, float* sh2,
                              float* wcf, float* bcf) {
    const int isbf = *flagp;
    const int i = threadIdx.x;  // 512
    float s1 = ldsel(g1, i, isbf) / sqrtf(ldsel(v1, i, isbf) + 1e-5f);
    sc1[i] = s1;
    sh1[i] = (ldsel(b1, i, isbf) - ldsel(m1, i, isbf)) * s1 + ldsel(be1, i, isbf);
    float s2 = ldsel(g2, i, isbf) / sqrtf(ldsel(v2, i, isbf) + 1e-5f);
    sc2[i] = s2;
    sh2[i] = (ldsel(b2, i, isbf) - ldsel(m2, i, isbf)) * s2 + ldsel(be2, i, isbf);
    wcf[i] = ldsel(Wc, i, isbf);
    wcf[512 + i] = ldsel(Wc, 512 + i, isbf);
    if (i < 2) bcf[i] = ldsel(bc, i, isbf);
}

// ---- prep: W1,W2 -> bf16 in FRAGMENT-MAJOR order ----
__global__ void wconv_kernel(const void* __restrict__ W1, const void* __restrict__ W2,
                             const int* __restrict__ flagp,
                             bf16_t* __restrict__ W1pk, bf16_t* __restrict__ W2pk) {
    const int isbf = *flagp;
    const int t = blockIdx.x * 256 + threadIdx.x;   // 0..32767
    const int lane = t & 63;
    const int kt = (t >> 6) & 15;
    const int c16 = t >> 10;
    const int src = (c16 * 16 + (lane & 15)) * 512 + kt * 32 + (lane >> 4) * 8;
    bf16x8 v1, v2;
    #pragma unroll
    for (int e = 0; e < 8; ++e) {
        v1[e] = (__bf16)ldsel(W1, src + e, isbf);
        v2[e] = (__bf16)ldsel(W2, src + e, isbf);
    }
    *reinterpret_cast<bf16x8*>(W1pk + (size_t)t * 8) = v1;
    *reinterpret_cast<bf16x8*>(W2pk + (size_t)t * 8) = v2;
}

// ---- prep: wn_t[n][m] = w_norm[m][n] ----
__global__ void wnorm_kernel(const void* __restrict__ w, const int* __restrict__ flagp,
                             const float* __restrict__ dinv, float* __restrict__ wn_t) {
    const int isbf = *flagp;
    const int idx = blockIdx.x * 256 + threadIdx.x;   // 262144
    const int n = idx >> 9, m = idx & 511;
    float a = ldsel(w, n * 512 + m, isbf) + (m == n ? 1.0f : 0.0f);
    wn_t[idx] = a * dinv[m] * dinv[n];
}

#define FJSTRIDE 16384
#define FKSTRIDE 1024

#define LOADW4(dst, base, kt)                                                  \
    _Pragma("unroll")                                                          \
    for (int j_ = 0; j_ < 4; ++j_)                                             \
        dst[j_] = *reinterpret_cast<const bf16x8*>((base) + j_ * FJSTRIDE + (kt) * FKSTRIDE);

#define MFMA16(bset, aset)                                                     \
    _Pragma("unroll")                                                          \
    for (int j_ = 0; j_ < 4; ++j_)                                             \
        _Pragma("unroll")                                                      \
        for (int i_ = 0; i_ < 4; ++i_)                                         \
            acc[j_][i_] = __builtin_amdgcn_mfma_f32_16x16x32_bf16(bset[j_], aset[i_], acc[j_][i_], 0, 0, 0);

// read 4 A-frags for k-tile kt from fragment-major Afm (conflict-free)
#define LDAF(dst, kt)                                                          \
    _Pragma("unroll")                                                          \
    for (int i_ = 0; i_ < 4; ++i_)                                             \
        dst[i_] = *reinterpret_cast<const bf16x8*>(                            \
            (const char*)Afm + (((i_ * 16 + (kt)) * 64) + lane) * 16);

// read 4 T1 frags for k-tile kt from row-major swizzled T1s
#define LDT1(dst, kt)                                                          \
    _Pragma("unroll")                                                          \
    for (int i_ = 0; i_ < 4; ++i_) {                                           \
        const int row_ = i_ * 16 + rl;                                         \
        int off_ = (row_ << 10) + (kt) * 64 + hi * 16;                         \
        off_ ^= (row_ & 7) << 4;                                               \
        dst[i_] = *reinterpret_cast<const bf16x8*>((const char*)T1s + off_);   \
    }

// issue the whole A-tile's global loads for tile T into sA/sAb registers
#define STAGE_ISSUE(T)                                                         \
    {                                                                          \
        const size_t gb_ = ((size_t)((T) * BM) + srow) * KDIM + sc8 * 8;       \
        if (isbf) {                                                            \
            const bf16_t* Ab_ = (const bf16_t*)A + gb_;                        \
            _Pragma("unroll")                                                  \
            for (int it = 0; it < 8; ++it)                                     \
                sAb[it] = *reinterpret_cast<const bf16x8*>(Ab_ + it * 64);     \
        } else {                                                               \
            const float* Af_ = (const float*)A + gb_;                          \
            _Pragma("unroll")                                                  \
            for (int it = 0; it < 8; ++it) {                                   \
                sA[2 * it]     = *reinterpret_cast<const f32x4*>(Af_ + it * 64);     \
                sA[2 * it + 1] = *reinterpret_cast<const f32x4*>(Af_ + it * 64 + 4); \
            }                                                                  \
        }                                                                      \
    }

// convert + ds_write the staged registers into fragment-major Afm
#define STAGE_WRITE()                                                          \
    _Pragma("unroll")                                                          \
    for (int it = 0; it < 8; ++it) {                                           \
        const int c8_ = sc8 + it * 8;                                          \
        const int off_ = ((((srow >> 4) * 16 + (c8_ >> 2)) * 64)               \
                          + (srow & 15) + (c8_ & 3) * 16) * 16;                \
        bf16x8 v_;                                                             \
        if (isbf) { v_ = sAb[it]; }                                            \
        else {                                                                 \
            f32x4 a0_ = sA[2 * it], a1_ = sA[2 * it + 1];                      \
            v_[0]=(__bf16)a0_.x; v_[1]=(__bf16)a0_.y; v_[2]=(__bf16)a0_.z; v_[3]=(__bf16)a0_.w; \
            v_[4]=(__bf16)a1_.x; v_[5]=(__bf16)a1_.y; v_[6]=(__bf16)a1_.z; v_[7]=(__bf16)a1_.w; \
        }                                                                      \
        *reinterpret_cast<bf16x8*>((char*)Afm + off_) = v_;                    \
    }

// ---- fused MLP: persistent 256 blocks x 4 tiles, 8 waves, barrier-free K-loops ----
__launch_bounds__(512, 2)
__global__ void fused_mlp(const void* __restrict__ A,      // d: f32 or bf16, 65536x512
                          const bf16_t* __restrict__ W1pk, // fragment-major bf16
                          const bf16_t* __restrict__ W2pk,
                          const float* __restrict__ sc1, const float* __restrict__ sh1,
                          const float* __restrict__ sc2, const float* __restrict__ sh2,
                          const float* __restrict__ wcf,   // 1024 f32
                          const int* __restrict__ flagp,
                          float* __restrict__ U)           // 65536 x 2
{
    __shared__ __align__(16) bf16_t Afm[BM * KDIM];   // 64 KB fragment-major A tile
    __shared__ __align__(16) bf16_t T1s[BM * KDIM];   // 64 KB row-major swizzled
    __shared__ float Ured[8][BM][2];                  // 4 KB

    const int isbf = *flagp;
    const int tid = threadIdx.x;
    const int wave = tid >> 6, lane = tid & 63;
    const int rl = lane & 15, hi = lane >> 4;
    const int wc = wave;                        // wave owns cols wc*64..+64
    const int bid = blockIdx.x;                 // 0..255; tiles bid*4..bid*4+3

    const char* w1base = (const char*)W1pk + ((size_t)(wc * 4) * 16 * 64 + lane) * 16;
    const char* w2base = (const char*)W2pk + ((size_t)(wc * 4) * 16 * 64 + lane) * 16;

    // staging coords: thread covers row srow, 8-elem chunks sc8, sc8+8, ...
    const int srow = tid >> 3;                  // 0..63
    const int sc8 = tid & 7;                    // 0..7

    f32x4 sA[16];
    bf16x8 sAb[8];

    // prologue: stage tile bid*4
    STAGE_ISSUE(bid * 4);
    STAGE_WRITE();
    __syncthreads();

    for (int t = 0; t < 4; ++t) {
        const int tile = bid * 4 + t;

        // ================= phase 1: T1 = lrelu(bn1(A @ W1^T)) — no barriers =====
        {
            f32x4 acc[4][4] = {};
            bf16x8 bW0[4], bW1[4], aT0[4], aT1[4];
            LOADW4(bW0, w1base, 0);
            LDAF(aT0, 0);
            #pragma unroll 1
            for (int kt = 0; kt < 16; kt += 2) {
                LOADW4(bW1, w1base, kt + 1);
                LDAF(aT1, kt + 1);
                MFMA16(bW0, aT0);
                if (kt + 2 < 16) { LOADW4(bW0, w1base, kt + 2); LDAF(aT0, kt + 2); }
                MFMA16(bW1, aT1);
            }
            // epilogue 1: BN + LReLU -> swizzled T1s
            #pragma unroll
            for (int j = 0; j < 4; ++j) {
                const int col0 = wc * 64 + j * 16 + hi * 4;
                const f32x4 s4 = *reinterpret_cast<const f32x4*>(&sc1[col0]);
                const f32x4 h4 = *reinterpret_cast<const f32x4*>(&sh1[col0]);
                #pragma unroll
                for (int i = 0; i < 4; ++i) {
                    const int row = i * 16 + rl;
                    int off = (row << 10) + (col0 << 1);
                    off ^= (row & 7) << 4;
                    bf16x4 pk;
                    #pragma unroll
                    for (int r = 0; r < 4; ++r) {
                        float y = acc[j][i][r] * s4[r] + h4[r];
                        y = y > 0.f ? y : 0.1f * y;
                        pk[r] = (__bf16)y;
                    }
                    *reinterpret_cast<bf16x4*>((char*)T1s + off) = pk;
                }
            }
        }
        __syncthreads();   // T1s visible; Afm fully consumed

        // issue next tile's A loads (in flight during phase 2)
        if (t < 3) STAGE_ISSUE(tile + 1);

        // ================= phase 2: U = proj(lrelu(bn2(T1 @ W2^T))) — no barriers ==
        float p0[4] = {0.f, 0.f, 0.f, 0.f}, p1[4] = {0.f, 0.f, 0.f, 0.f};
        {
            f32x4 acc[4][4] = {};
            bf16x8 bW0[4], bW1[4], aT0[4], aT1[4];
            LOADW4(bW0, w2base, 0);
            LDT1(aT0, 0);
            #pragma unroll 1
            for (int kt = 0; kt < 16; kt += 2) {
                LOADW4(bW1, w2base, kt + 1);
                LDT1(aT1, kt + 1);
                MFMA16(bW0, aT0);
                if (kt + 2 < 16) { LOADW4(bW0, w2base, kt + 2); LDT1(aT0, kt + 2); }
                MFMA16(bW1, aT1);
            }
            // commit next tile's A into Afm (safe: all waves past the epi1 barrier)
            if (t < 3) STAGE_WRITE();

            // epilogue 2: BN + LReLU + 512->2 projection
            #pragma unroll
            for (int j = 0; j < 4; ++j) {
                const int col0 = wc * 64 + j * 16 + hi * 4;
                const f32x4 s4 = *reinterpret_cast<const f32x4*>(&sc2[col0]);
                const f32x4 h4 = *reinterpret_cast<const f32x4*>(&sh2[col0]);
                const f32x4 w0 = *reinterpret_cast<const f32x4*>(&wcf[col0]);
                const f32x4 w1 = *reinterpret_cast<const f32x4*>(&wcf[512 + col0]);
                #pragma unroll
                for (int i = 0; i < 4; ++i)
                    #pragma unroll
                    for (int r = 0; r < 4; ++r) {
                        float y = acc[j][i][r] * s4[r] + h4[r];
                        y = y > 0.f ? y : 0.1f * y;
                        p0[i] += y * w0[r];
                        p1[i] += y * w1[r];
                    }
            }
        }
        #pragma unroll
        for (int i = 0; i < 4; ++i) {
            float a = p0[i], b = p1[i];
            a += __shfl_xor(a, 16, 64);  b += __shfl_xor(b, 16, 64);
            a += __shfl_xor(a, 32, 64);  b += __shfl_xor(b, 32, 64);
            if (hi == 0) {
                Ured[wc][i * 16 + rl][0] = a;
                Ured[wc][i * 16 + rl][1] = b;
            }
        }
        __syncthreads();   // Ured ready; Afm staging writes drained for next tile
        if (tid < BM * 2) {
            const int row = tid >> 1, c = tid & 1;
            float s = 0.f;
            #pragma unroll
            for (int q = 0; q < 8; ++q) s += Ured[q][row][c];
            U[(size_t)(tile * BM + row) * 2 + c] = s;
        }
    }
}

// ---- GCN on 2-wide features ----
__global__ void gcn_kernel(const float* __restrict__ wn_t, const float* __restrict__ U,
                           const float* __restrict__ bcf, const int* __restrict__ flagp,
                           void* __restrict__ out) {
    const int isbf = *flagp;
    const int wave = threadIdx.x >> 6, lane = threadIdx.x & 63;
    const int task = blockIdx.x * 4 + wave;   // (b, n)
    const int b = task >> 9, n = task & 511;
    const float* wrow = wn_t + n * 512;
    const float* ub = U + b * 1024;
    float a0 = 0.f, a1 = 0.f;
    for (int m = lane; m < 512; m += 64) {
        const float wv = wrow[m];
        a0 += wv * ub[m * 2];
        a1 += wv * ub[m * 2 + 1];
    }
    #pragma unroll
    for (int off = 32; off; off >>= 1) {
        a0 += __shfl_down(a0, off, 64);
        a1 += __shfl_down(a1, off, 64);
    }
    if (lane == 0) {
        const float r0 = a0 + bcf[0];
        const float r1 = a1 + bcf[1];
        if (isbf) {
            ((bf16_t*)out)[task * 2]     = __float2bfloat16(r0);
            ((bf16_t*)out)[task * 2 + 1] = __float2bfloat16(r1);
        } else {
            ((float*)out)[task * 2]     = r0;
            ((float*)out)[task * 2 + 1] = r1;
        }
    }
}

extern "C" void kernel_launch(void* const* d_in, const int* in_sizes, int n_in,
                              void* d_out, int out_size, void* d_ws, size_t ws_size,
                              hipStream_t stream) {
    const void* d   = d_in[0];
    const void* w   = d_in[1];
    const void* W1  = d_in[2];
    const void* b1  = d_in[3];
    const void* g1  = d_in[4];
    const void* be1 = d_in[5];
    const void* m1  = d_in[6];
    const void* v1  = d_in[7];
    const void* W2  = d_in[8];
    const void* b2  = d_in[9];
    const void* g2  = d_in[10];
    const void* be2 = d_in[11];
    const void* m2  = d_in[12];
    const void* v2  = d_in[13];
    const void* Wc  = d_in[14];
    const void* bc  = d_in[15];

    // workspace layout: ~2.6 MB total
    char* ws = (char*)d_ws;
    float*  wn_t = (float*)ws;                         // 1 MB
    bf16_t* W1pk = (bf16_t*)(ws + 0x100000);           // 512 KB (fragment-major)
    bf16_t* W2pk = (bf16_t*)(ws + 0x180000);           // 512 KB
    float*  sc1  = (float*)(ws + 0x200000);
    float*  sh1  = sc1 + 512;
    float*  sc2  = sh1 + 512;
    float*  sh2  = sc2 + 512;
    float*  dinv = sh2 + 512;
    float*  wcf  = (float*)(ws + 0x204000);            // 4 KB
    float*  bcf  = (float*)(ws + 0x205000);
    int*    flag = (int*)(ws + 0x205100);
    float*  U    = (float*)(ws + 0x208000);            // 512 KB

    const int M = 128 * 512;   // 65536 rows

    probe_kernel<<<1, 64, 0, stream>>>(d, flag);
    rowsum_kernel<<<512, 64, 0, stream>>>(w, flag, dinv);
    params_kernel<<<1, 512, 0, stream>>>(g1, b1, m1, v1, be1, g2, b2, m2, v2, be2,
                                         Wc, bc, flag, sc1, sh1, sc2, sh2, wcf, bcf);
    wconv_kernel<<<128, 256, 0, stream>>>(W1, W2, flag, W1pk, W2pk);
    wnorm_kernel<<<1024, 256, 0, stream>>>(w, flag, dinv, wn_t);

    fused_mlp<<<256, 512, 0, stream>>>(d, W1pk, W2pk,
                                       sc1, sh1, sc2, sh2, wcf, flag, U);

    gcn_kernel<<<M / 4, 256, 0, stream>>>(wn_t, U, bcf, flag, d_out);
}

// Round 16
// 128.700 us; speedup vs baseline: 1.7002x; 1.7002x over previous
//
#include <hip/hip_runtime.h>
#include <hip/hip_bf16.h>

// Sggnn_gcn — fused 2x(Linear512+BN+LReLU) + Wc projection, then GCN on 2-wide
// features. Restructuring: (w_norm^T @ t) @ Wc^T == w_norm^T @ (t @ Wc^T).
// v16: BM=64, 8-wave blocks, LDS 80 KB -> TWO independent blocks/CU (stall
// hiding v9-v15 never had), A staged as raw f32 via global_load_lds width=16
// with swizzled SOURCE addresses (linear LDS dest, m173), f32->bf16 cvt at
// fragment build. Phase-1: 1 barrier/kt (m97 discipline); phase-2 barrier-free
// from swizzled T1s. Reg budget pinned ~110 <= 128 (launch_bounds(512,4)).

typedef __hip_bfloat16 bf16_t;
typedef __bf16 bf16x8 __attribute__((ext_vector_type(8)));
typedef __bf16 bf16x4 __attribute__((ext_vector_type(4)));
typedef float f32x4 __attribute__((ext_vector_type(4)));

#define KDIM 512
#define BM 64

__device__ __forceinline__ void gload_lds16(const void* g, void* l) {
    __builtin_amdgcn_global_load_lds(
        (const __attribute__((address_space(1))) unsigned int*)g,
        (__attribute__((address_space(3))) unsigned int*)l,
        16, 0, 0);
}

__device__ __forceinline__ float ldsel(const void* p, int i, int isbf) {
    return isbf ? __bfloat162float(((const bf16_t*)p)[i]) : ((const float*)p)[i];
}

// ---- probe: detect dtype of d (bf16 vs f32) from exponent statistics ----
__global__ void probe_kernel(const void* __restrict__ d, int* __restrict__ flag) {
    const unsigned short* u = (const unsigned short*)d;
    const int l = threadIdx.x;   // 64
    int cnt = 0;
    for (int i = l; i < 256; i += 64) {
        const int e = (u[i] >> 7) & 0xFF;
        cnt += (e >= 118 && e <= 129) ? 1 : 0;
    }
    #pragma unroll
    for (int off = 32; off; off >>= 1) cnt += __shfl_down(cnt, off, 64);
    if (l == 0) *flag = (cnt >= 200) ? 1 : 0;   // bf16 ~255, f32 ~134
}

// ---- prep: rowsum of adj = w + I  ->  d_inv_sqrt ----
__global__ void rowsum_kernel(const void* __restrict__ w, const int* __restrict__ flagp,
                              float* __restrict__ dinv) {
    const int isbf = *flagp;
    const int i = blockIdx.x;
    const int l = threadIdx.x;
    float s = 0.f;
    for (int j = l; j < 512; j += 64) s += ldsel(w, i * 512 + j, isbf);
    #pragma unroll
    for (int off = 32; off; off >>= 1) s += __shfl_down(s, off, 64);
    if (l == 0) dinv[i] = 1.0f / sqrtf(s + 1.0f);
}

// ---- prep: fold BN -> scale/shift; canonicalize Wc, bc to f32 ----
__global__ void params_kernel(const void* g1, const void* b1, const void* m1,
                              const void* v1, const void* be1,
                              const void* g2, const void* b2, const void* m2,
                              const void* v2, const void* be2,
                              const void* Wc, const void* bc,
                              const int* __restrict__ flagp,
                              float* sc1, float* sh1, float* sc2, float* sh2,
                              float* wcf, float* bcf) {
    const int isbf = *flagp;
    const int i = threadIdx.x;  // 512
    float s1 = ldsel(g1, i, isbf) / sqrtf(ldsel(v1, i, isbf) + 1e-5f);
    sc1[i] = s1;
    sh1[i] = (ldsel(b1, i, isbf) - ldsel(m1, i, isbf)) * s1 + ldsel(be1, i, isbf);
    float s2 = ldsel(g2, i, isbf) / sqrtf(ldsel(v2, i, isbf) + 1e-5f);
    sc2[i] = s2;
    sh2[i] = (ldsel(b2, i, isbf) - ldsel(m2, i, isbf)) * s2 + ldsel(be2, i, isbf);
    wcf[i] = ldsel(Wc, i, isbf);
    wcf[512 + i] = ldsel(Wc, 512 + i, isbf);
    if (i < 2) bcf[i] = ldsel(bc, i, isbf);
}

// ---- prep: W1,W2 -> bf16 in FRAGMENT-MAJOR order ----
__global__ void wconv_kernel(const void* __restrict__ W1, const void* __restrict__ W2,
                             const int* __restrict__ flagp,
                             bf16_t* __restrict__ W1pk, bf16_t* __restrict__ W2pk) {
    const int isbf = *flagp;
    const int t = blockIdx.x * 256 + threadIdx.x;   // 0..32767
    const int lane = t & 63;
    const int kt = (t >> 6) & 15;
    const int c16 = t >> 10;
    const int src = (c16 * 16 + (lane & 15)) * 512 + kt * 32 + (lane >> 4) * 8;
    bf16x8 v1, v2;
    #pragma unroll
    for (int e = 0; e < 8; ++e) {
        v1[e] = (__bf16)ldsel(W1, src + e, isbf);
        v2[e] = (__bf16)ldsel(W2, src + e, isbf);
    }
    *reinterpret_cast<bf16x8*>(W1pk + (size_t)t * 8) = v1;
    *reinterpret_cast<bf16x8*>(W2pk + (size_t)t * 8) = v2;
}

// ---- prep: wn_t[n][m] = w_norm[m][n] ----
__global__ void wnorm_kernel(const void* __restrict__ w, const int* __restrict__ flagp,
                             const float* __restrict__ dinv, float* __restrict__ wn_t) {
    const int isbf = *flagp;
    const int idx = blockIdx.x * 256 + threadIdx.x;   // 262144
    const int n = idx >> 9, m = idx & 511;
    float a = ldsel(w, n * 512 + m, isbf) + (m == n ? 1.0f : 0.0f);
    wn_t[idx] = a * dinv[m] * dinv[n];
}

#define FJSTRIDE 16384
#define FKSTRIDE 1024

#define LOADW4(dst, base, kt)                                                  \
    _Pragma("unroll")                                                          \
    for (int j_ = 0; j_ < 4; ++j_)                                             \
        dst[j_] = *reinterpret_cast<const bf16x8*>((base) + j_ * FJSTRIDE + (kt) * FKSTRIDE);

// stage A k-tile kt (f32 layout, chunk-swizzled) into AsgF[buf].
// LDS chunk q=tid holds global chunk c = (q&7)^(row&7), row = q>>3.
#define STAGE(kt, buf)                                                         \
    {                                                                          \
        if (isbf) {                                                            \
            const bf16_t* sp_ = (const bf16_t*)A + sgb + (size_t)(kt) * 32;    \
            bf16x4 b4_ = *reinterpret_cast<const bf16x4*>(sp_);                \
            f32x4 f_;                                                          \
            f_.x = (float)b4_[0]; f_.y = (float)b4_[1];                        \
            f_.z = (float)b4_[2]; f_.w = (float)b4_[3];                        \
            *reinterpret_cast<f32x4*>((char*)AsgF + (buf) * 8192 + tid * 16) = f_; \
        } else {                                                               \
            gload_lds16((const char*)A + (sgb + (size_t)(kt) * 32) * 4,        \
                        (char*)AsgF + (buf) * 8192 + wave * 1024);             \
        }                                                                      \
    }

// ds_read f32 frag (2 swizzled b128) + cvt -> bf16x8 + 4 MFMA, for i=0..3
#define COMPUTE(kt, buf, bWs)                                                  \
    _Pragma("unroll")                                                          \
    for (int i_ = 0; i_ < 4; ++i_) {                                           \
        const int r_ = i_ * 16 + rl;                                           \
        const int rb_ = (buf) * 8192 + r_ * 128;                               \
        const int s_ = r_ & 7;                                                 \
        f32x4 q0_ = *reinterpret_cast<const f32x4*>(                           \
            (const char*)AsgF + rb_ + (((2 * hi) ^ s_) << 4));                 \
        f32x4 q1_ = *reinterpret_cast<const f32x4*>(                           \
            (const char*)AsgF + rb_ + (((2 * hi + 1) ^ s_) << 4));             \
        bf16x8 af_;                                                            \
        af_[0]=(__bf16)q0_.x; af_[1]=(__bf16)q0_.y; af_[2]=(__bf16)q0_.z; af_[3]=(__bf16)q0_.w; \
        af_[4]=(__bf16)q1_.x; af_[5]=(__bf16)q1_.y; af_[6]=(__bf16)q1_.z; af_[7]=(__bf16)q1_.w; \
        _Pragma("unroll")                                                      \
        for (int j_ = 0; j_ < 4; ++j_)                                         \
            acc[j_][i_] = __builtin_amdgcn_mfma_f32_16x16x32_bf16(bWs[j_], af_, acc[j_][i_], 0, 0, 0); \
    }

// T1s frag read + 4x4 MFMA (phase 2)
#define COMPT1(kt, bWs)                                                        \
    _Pragma("unroll")                                                          \
    for (int i_ = 0; i_ < 4; ++i_) {                                           \
        const int row_ = i_ * 16 + rl;                                         \
        int off_ = (row_ << 10) + (kt) * 64 + hi * 16;                         \
        off_ ^= (row_ & 7) << 4;                                               \
        bf16x8 af_ = *reinterpret_cast<const bf16x8*>((const char*)T1s + off_);\
        _Pragma("unroll")                                                      \
        for (int j_ = 0; j_ < 4; ++j_)                                         \
            acc[j_][i_] = __builtin_amdgcn_mfma_f32_16x16x32_bf16(bWs[j_], af_, acc[j_][i_], 0, 0, 0); \
    }

// ---- fused MLP: 8 waves, BM=64, 2 blocks/CU; DMA-staged f32 A; T1 in LDS ----
__launch_bounds__(512, 4)
__global__ void fused_mlp(const void* __restrict__ A,      // d: f32 or bf16, 65536x512
                          const bf16_t* __restrict__ W1pk, // fragment-major bf16
                          const bf16_t* __restrict__ W2pk,
                          const float* __restrict__ sc1, const float* __restrict__ sh1,
                          const float* __restrict__ sc2, const float* __restrict__ sh2,
                          const float* __restrict__ wcf,   // 1024 f32
                          const int* __restrict__ flagp,
                          float* __restrict__ U)           // 65536 x 2
{
    __shared__ __align__(16) bf16_t T1s[BM * KDIM];   // 64 KB row-major swizzled
    __shared__ __align__(16) float AsgF[2][BM * 32];  // 2 x 8 KB f32, chunk-swizzled
    float* UredF = (float*)AsgF;                      // 4 KB overlay after phase 1

    const int isbf = *flagp;
    const int tid = threadIdx.x;
    const int wave = tid >> 6, lane = tid & 63;
    const int rl = lane & 15, hi = lane >> 4;
    const int wc = wave;                        // wave owns cols wc*64..+64
    const int tile = blockIdx.x;                // 0..1023; rows tile*64..+64

    const char* w1base = (const char*)W1pk + ((size_t)(wc * 4) * 16 * 64 + lane) * 16;
    const char* w2base = (const char*)W2pk + ((size_t)(wc * 4) * 16 * 64 + lane) * 16;

    // staging source mapping: LDS chunk q=tid -> row q>>3, global chunk (q&7)^(row&7)
    const int srow = tid >> 3;
    const int schk = (tid & 7) ^ (srow & 7);
    const size_t sgb = ((size_t)(tile * BM) + srow) * KDIM + schk * 4;  // element idx

    f32x4 acc[4][4] = {};

    // ================= phase 1: T1 = lrelu(bn1(A @ W1^T)) =================
    STAGE(0, 0);
    __syncthreads();   // buf0 ready (drains DMA / ds_write)

    {
        bf16x8 bW[4];
        #pragma unroll 1
        for (int kt = 0; kt < 16; ++kt) {
            if (kt + 1 < 16) STAGE(kt + 1, (kt + 1) & 1);   // flies during compute
            LOADW4(bW, w1base, kt);
            COMPUTE(kt, kt & 1, bW);
            __syncthreads();   // next buf staged; this buf's reads done
        }
    }

    // epilogue 1: BN + LReLU -> swizzled T1s
    #pragma unroll
    for (int j = 0; j < 4; ++j) {
        const int col0 = wc * 64 + j * 16 + hi * 4;
        const f32x4 s4 = *reinterpret_cast<const f32x4*>(&sc1[col0]);
        const f32x4 h4 = *reinterpret_cast<const f32x4*>(&sh1[col0]);
        #pragma unroll
        for (int i = 0; i < 4; ++i) {
            const int row = i * 16 + rl;
            int off = (row << 10) + (col0 << 1);
            off ^= (row & 7) << 4;
            bf16x4 pk;
            #pragma unroll
            for (int r = 0; r < 4; ++r) {
                float y = acc[j][i][r] * s4[r] + h4[r];
                y = y > 0.f ? y : 0.1f * y;
                pk[r] = (__bf16)y;
            }
            *reinterpret_cast<bf16x4*>((char*)T1s + off) = pk;
        }
    }
    __syncthreads();   // T1s visible to all waves

    // ================= phase 2: U = proj(lrelu(bn2(T1 @ W2^T))) — barrier-free ==
    #pragma unroll
    for (int j = 0; j < 4; ++j)
        #pragma unroll
        for (int i = 0; i < 4; ++i)
            acc[j][i] = f32x4{0.f, 0.f, 0.f, 0.f};

    {
        bf16x8 bW0[4], bW1[4];
        LOADW4(bW0, w2base, 0);
        #pragma unroll 1
        for (int kt = 0; kt < 16; kt += 2) {
            LOADW4(bW1, w2base, kt + 1);
            COMPT1(kt, bW0);
            if (kt + 2 < 16) LOADW4(bW0, w2base, kt + 2);
            COMPT1(kt + 1, bW1);
        }
    }

    // epilogue 2: BN + LReLU + 512->2 projection
    float p0[4] = {0.f, 0.f, 0.f, 0.f}, p1[4] = {0.f, 0.f, 0.f, 0.f};
    #pragma unroll
    for (int j = 0; j < 4; ++j) {
        const int col0 = wc * 64 + j * 16 + hi * 4;
        const f32x4 s4 = *reinterpret_cast<const f32x4*>(&sc2[col0]);
        const f32x4 h4 = *reinterpret_cast<const f32x4*>(&sh2[col0]);
        const f32x4 w0 = *reinterpret_cast<const f32x4*>(&wcf[col0]);
        const f32x4 w1 = *reinterpret_cast<const f32x4*>(&wcf[512 + col0]);
        #pragma unroll
        for (int i = 0; i < 4; ++i)
            #pragma unroll
            for (int r = 0; r < 4; ++r) {
                float y = acc[j][i][r] * s4[r] + h4[r];
                y = y > 0.f ? y : 0.1f * y;
                p0[i] += y * w0[r];
                p1[i] += y * w1[r];
            }
    }
    #pragma unroll
    for (int i = 0; i < 4; ++i) {
        float a = p0[i], b = p1[i];
        a += __shfl_xor(a, 16, 64);  b += __shfl_xor(b, 16, 64);
        a += __shfl_xor(a, 32, 64);  b += __shfl_xor(b, 32, 64);
        if (hi == 0) {
            UredF[(wc * BM + i * 16 + rl) * 2]     = a;
            UredF[(wc * BM + i * 16 + rl) * 2 + 1] = b;
        }
    }
    __syncthreads();
    if (tid < BM * 2) {
        const int row = tid >> 1, c = tid & 1;
        float s = 0.f;
        #pragma unroll
        for (int q = 0; q < 8; ++q) s += UredF[(q * BM + row) * 2 + c];
        U[(size_t)(tile * BM + row) * 2 + c] = s;
    }
}

// ---- GCN on 2-wide features ----
__global__ void gcn_kernel(const float* __restrict__ wn_t, const float* __restrict__ U,
                           const float* __restrict__ bcf, const int* __restrict__ flagp,
                           void* __restrict__ out) {
    const int isbf = *flagp;
    const int wave = threadIdx.x >> 6, lane = threadIdx.x & 63;
    const int task = blockIdx.x * 4 + wave;   // (b, n)
    const int b = task >> 9, n = task & 511;
    const float* wrow = wn_t + n * 512;
    const float* ub = U + b * 1024;
    float a0 = 0.f, a1 = 0.f;
    for (int m = lane; m < 512; m += 64) {
        const float wv = wrow[m];
        a0 += wv * ub[m * 2];
        a1 += wv * ub[m * 2 + 1];
    }
    #pragma unroll
    for (int off = 32; off; off >>= 1) {
        a0 += __shfl_down(a0, off, 64);
        a1 += __shfl_down(a1, off, 64);
    }
    if (lane == 0) {
        const float r0 = a0 + bcf[0];
        const float r1 = a1 + bcf[1];
        if (isbf) {
            ((bf16_t*)out)[task * 2]     = __float2bfloat16(r0);
            ((bf16_t*)out)[task * 2 + 1] = __float2bfloat16(r1);
        } else {
            ((float*)out)[task * 2]     = r0;
            ((float*)out)[task * 2 + 1] = r1;
        }
    }
}

extern "C" void kernel_launch(void* const* d_in, const int* in_sizes, int n_in,
                              void* d_out, int out_size, void* d_ws, size_t ws_size,
                              hipStream_t stream) {
    const void* d   = d_in[0];
    const void* w   = d_in[1];
    const void* W1  = d_in[2];
    const void* b1  = d_in[3];
    const void* g1  = d_in[4];
    const void* be1 = d_in[5];
    const void* m1  = d_in[6];
    const void* v1  = d_in[7];
    const void* W2  = d_in[8];
    const void* b2  = d_in[9];
    const void* g2  = d_in[10];
    const void* be2 = d_in[11];
    const void* m2  = d_in[12];
    const void* v2  = d_in[13];
    const void* Wc  = d_in[14];
    const void* bc  = d_in[15];

    // workspace layout: ~2.6 MB total
    char* ws = (char*)d_ws;
    float*  wn_t = (float*)ws;                         // 1 MB
    bf16_t* W1pk = (bf16_t*)(ws + 0x100000);           // 512 KB (fragment-major)
    bf16_t* W2pk = (bf16_t*)(ws + 0x180000);           // 512 KB
    float*  sc1  = (float*)(ws + 0x200000);
    float*  sh1  = sc1 + 512;
    float*  sc2  = sh1 + 512;
    float*  sh2  = sc2 + 512;
    float*  dinv = sh2 + 512;
    float*  wcf  = (float*)(ws + 0x204000);            // 4 KB
    float*  bcf  = (float*)(ws + 0x205000);
    int*    flag = (int*)(ws + 0x205100);
    float*  U    = (float*)(ws + 0x208000);            // 512 KB

    const int M = 128 * 512;   // 65536 rows

    probe_kernel<<<1, 64, 0, stream>>>(d, flag);
    rowsum_kernel<<<512, 64, 0, stream>>>(w, flag, dinv);
    params_kernel<<<1, 512, 0, stream>>>(g1, b1, m1, v1, be1, g2, b2, m2, v2, be2,
                                         Wc, bc, flag, sc1, sh1, sc2, sh2, wcf, bcf);
    wconv_kernel<<<128, 256, 0, stream>>>(W1, W2, flag, W1pk, W2pk);
    wnorm_kernel<<<1024, 256, 0, stream>>>(w, flag, dinv, wn_t);

    fused_mlp<<<M / BM, 512, 0, stream>>>(d, W1pk, W2pk,
                                          sc1, sh1, sc2, sh2, wcf, flag, U);

    gcn_kernel<<<M / 4, 256, 0, stream>>>(wn_t, U, bcf, flag, d_out);
}